// Round 11
// baseline (181.620 us; speedup 1.0000x reference)
//
#include <hip/hip_runtime.h>
#include <stdint.h>

#define G_   250
#define P_   200
#define EPG  3200
#define E_   800000
#define F_   128
#define R_   8
#define HROW 136   // f16 elems per row; 272 B stride, 16B-aligned rows
#define NKEY (R_ * P_)   // 1600 (rel,dst) buckets
#define BSTG (8 * 4 * 64 * 8)   // 16384 f16 = 32 KB per (l,r) B-fragment set

typedef _Float16 f16x8 __attribute__((ext_vector_type(8)));
typedef _Float16 f16x4 __attribute__((ext_vector_type(4)));
typedef float    f32x4 __attribute__((ext_vector_type(4)));
typedef float    f32x16 __attribute__((ext_vector_type(16)));

// ---------------- prepass: W -> B-fragment layout for mfma_f32_32x32x16_f16 ----------------
// flat = ((((l*9+r)*8 + kt)*4 + ntj)*64 + lane)*8 + j
// value = W[r][k = kt*16 + (lane>>5)*8 + j][n = ntj*32 + (lane&31)]  (r==8 -> root)
__global__ __launch_bounds__(256) void k_wstage(const float* __restrict__ W1, const float* __restrict__ root1,
                                                const float* __restrict__ W2, const float* __restrict__ root2,
                                                _Float16* __restrict__ wf) {
  int t = blockIdx.x * 256 + threadIdx.x;   // exactly 1152*256 = 2*9*8*4*64*8
  int j    = t & 7;
  int lane = (t >> 3) & 63;
  int ntj  = (t >> 9) & 3;
  int kt   = (t >> 11) & 7;
  int rl_  = t >> 14;          // 0..17
  int r = rl_ % 9, l = rl_ / 9;
  const float* Wl = (l == 0) ? W1 : W2;
  const float* rt = (l == 0) ? root1 : root2;
  int k = kt * 16 + (lane >> 5) * 8 + j;
  int n = ntj * 32 + (lane & 31);
  float v = (r < 8) ? Wl[(r * F_ + k) * F_ + n] : rt[k * F_ + n];
  wf[t] = (_Float16)v;
}

// ---- gather+mean one relation's HALF-K A-fragments (4 chunks) for one dst row ----
__device__ __forceinline__ void gather4(f16x8 (&a)[4], const _Float16* __restrict__ Ap,
                                        const unsigned short* __restrict__ csr,
                                        const int* __restrict__ offs,
                                        int key, bool act, int cbck) {
  int o = 0, n = 0;
  if (act) { o = offs[key]; n = offs[key + 1] - o; }
  f16x8 z = {0, 0, 0, 0, 0, 0, 0, 0};
#pragma unroll
  for (int kt = 0; kt < 4; kt++) a[kt] = z;
  for (int t = 0; t < n; t++) {
    int s0 = (int)csr[o + t];
    const _Float16* hp = &Ap[s0 * HROW + cbck];
#pragma unroll
    for (int kt = 0; kt < 4; kt++) a[kt] += *((const f16x8*)(hp + kt * 16));
  }
  float nf = (n > 0) ? 1.0f / (float)n : 0.0f;
  _Float16 nh = (_Float16)nf;
#pragma unroll
  for (int kt = 0; kt < 4; kt++) a[kt] *= nh;
}

// ---------------- main: one workgroup = one graph; 16 waves = 8 tiles x 2 K-halves ----------
// Wave (t,H): tile t rows [t*25, t*25+25), input-K cols [H*64, H*64+64). Gather reads only
// its K-half (no duplication); 16 MFMAs/rel/wave accumulate PARTIAL sums over K. K-halves
// combine at layer end (L1: f32 staging through dead hbuf0; L2: partial scores add).
// amdgpu_waves_per_eu(4,4): pin min AND max occupancy so the allocator budget is 512/4 = 128
// VGPRs. R8/R9 showed __launch_bounds__(1024[,4]) lets the heuristic target 8 waves/EU
// (64 VGPRs) and spill 28 MB/dispatch to scratch. LDS (156 KB -> 1 block/CU = 4 waves/EU)
// means max=4 costs zero occupancy.
__global__ __launch_bounds__(1024) __attribute__((amdgpu_waves_per_eu(4, 4))) void k_main(
    const float* __restrict__ x, const int* __restrict__ ei, const int* __restrict__ et,
    const _Float16* __restrict__ wf, const float* __restrict__ b1, const float* __restrict__ b2,
    const float* __restrict__ message, const float* __restrict__ embed,
    const float* __restrict__ cw, const float* __restrict__ cb,
    const float* __restrict__ mw, const float* __restrict__ mb,
    float* __restrict__ out) {
  __shared__ __attribute__((aligned(16))) _Float16 hbuf0[P_ * HROW];  // 54400 B
  __shared__ __attribute__((aligned(16))) _Float16 hbuf1[P_ * HROW];  // 54400 B
  __shared__ __attribute__((aligned(16))) _Float16 Bstage[BSTG];      // 32768 B
  __shared__ unsigned short csrS[EPG];                                // 6400 B
  __shared__ int offsS[NKEY + 1];                                     // 6404 B
  __shared__ float msgS[F_ + 1];                                      // 516 B
  __shared__ float scoreS[2 * P_];                                    // 1600 B -> 156488 B

  int g = blockIdx.x, tid = threadIdx.x;
  int lane = tid & 63, wave = tid >> 6;
  int m32 = lane & 31, kh = lane >> 5;

  // ---- setup scratch aliased inside hbuf1 (dead before first odd-B commit) ----
  int*   Sint = (int*)hbuf1;
  int*   cnt  = Sint;                    // [1600]
  int*   cur  = Sint + 1600;             // [1600]
  int*   eRec = Sint + 3200;             // [3200]
  float* comb = (float*)(Sint + 6400);   // [256]
  float* red  = (float*)(Sint + 6656);   // [128]   => 27136 B < 54400 B

  // ---- issue (l=0, r=0) B loads immediately (land during phase 0): 2 x 16 B per thread ----
  f16x8 st0a = *((const f16x8*)(wf + tid * 8));
  f16x8 st0b = *((const f16x8*)(wf + 8192 + tid * 8));

  // ---- phase 0: stage x -> hbuf0 (f16); zero cnt/cur; msg combined features ----
  for (int i = tid; i < P_ * 32; i += 1024) {
    int row = i >> 5, c4 = i & 31;
    const float4 v = ((const float4*)x)[(g * P_ + row) * 32 + c4];
    f16x4 pk = { (_Float16)v.x, (_Float16)v.y, (_Float16)v.z, (_Float16)v.w };
    *((f16x4*)&hbuf0[row * HROW + c4 * 4]) = pk;
  }
  for (int i = tid; i < NKEY; i += 1024) { cnt[i] = 0; cur[i] = 0; }
  if (tid < F_) {
    int tok = (int)message[g * 2];
    float cont = message[g * 2 + 1];
    comb[tid] = embed[tok * F_ + tid];
    float ce = cont * cw[tid] + cb[tid];
    comb[F_ + tid] = ce > 0.0f ? ce : 0.0f;
  }
  *((f16x8*)(Bstage + tid * 8)) = st0a;
  *((f16x8*)(Bstage + 8192 + tid * 8)) = st0b;
  __syncthreads();

  // ---- phase 1 (wave-specialized): edge ingest (14 waves) || message matmul (2 waves) ----
  int base = g * EPG, nbase = g * P_;
  if (wave == 12 || wave == 13) {
    int col = tid & 127;
    float acc = 0.0f;
#pragma unroll 16
    for (int k2 = 0; k2 < 256; k2++) acc += comb[k2] * mw[k2 * F_ + col];
    red[col] = acc;
  } else {
    int iw = (wave < 12) ? wave : (wave - 2);
    for (int e = iw * 64 + lane; e < EPG; e += 896) {
      int s = ei[base + e] - nbase;
      int d = ei[E_ + base + e] - nbase;
      int r = et[base + e];
      eRec[e] = s | (d << 8) | (r << 16);
      atomicAdd(&cnt[r * P_ + d], 1);
    }
  }
  __syncthreads();

  // ---- phase 2: wave0 = offset scan (shfl); wave1 = msg finalize ----
  if (wave == 0) {
    int4 vv[8];
    int osum = 0;
    if (lane < 50) {
      const int4* cp = (const int4*)(cnt + lane * 32);
#pragma unroll
      for (int i = 0; i < 8; i++) { vv[i] = cp[i]; osum += vv[i].x + vv[i].y + vv[i].z + vv[i].w; }
    }
    int incl = osum;
#pragma unroll
    for (int d = 1; d < 64; d <<= 1) {
      int t2 = __shfl_up(incl, d, 64);
      if (lane >= d) incl += t2;
    }
    int run = incl - osum;   // exclusive prefix
    if (lane < 50) {
#pragma unroll
      for (int i = 0; i < 8; i++) {
        offsS[lane * 32 + i * 4 + 0] = run; run += vv[i].x;
        offsS[lane * 32 + i * 4 + 1] = run; run += vv[i].y;
        offsS[lane * 32 + i * 4 + 2] = run; run += vv[i].z;
        offsS[lane * 32 + i * 4 + 3] = run; run += vv[i].w;
      }
    }
    if (lane == 0) offsS[NKEY] = EPG;
  } else if (wave == 1) {
    float m0 = mb[lane] + red[lane];
    float m1 = mb[lane + 64] + red[lane + 64];
    m0 = m0 > 0.0f ? m0 : 0.0f;
    m1 = m1 > 0.0f ? m1 : 0.0f;
    msgS[lane] = m0; msgS[lane + 64] = m1;
    float p = m0 * b2[lane] + m1 * b2[lane + 64];
#pragma unroll
    for (int d = 32; d > 0; d >>= 1) p += __shfl_xor(p, d, 64);
    if (lane == 0) msgS[F_] = p;
  }
  __syncthreads();

  // ---- phase 3: CSR scatter from LDS records ----
  for (int e = tid; e < EPG; e += 1024) {
    int rec = eRec[e];
    int s = rec & 255, d = (rec >> 8) & 255, r = rec >> 16;
    int key = r * P_ + d;
    int pos = atomicAdd(&cur[key], 1);
    csrS[offsS[key] + pos] = (unsigned short)s;
  }
  __syncthreads();   // hbuf0 + csr + offs + msg + Bstage(l0,r0) ready; hbuf1 scratch dead

  // ---- fused layers ----
  int H = wave >> 3;          // K-half
  int t8 = wave & 7;          // tile
  int jobBase = t8 * 25;
  bool rowAct = (m32 < 25);
  int myD = jobBase + m32;
  int cbck = H * 64 + kh * 8;       // this lane's chunk base within a row
  int ktBase = H * 4;               // global kt range [ktBase, ktBase+4)
  int rowA = jobBase + (rowAct ? m32 : 24);

  for (int l = 0; l < 2; l++) {
    const _Float16* Ap = (l == 0) ? hbuf0 : hbuf1;
    _Float16* balt = (l == 0) ? hbuf1 : hbuf0;   // odd-r B buffer aliases the dead hbuf
    f32x16 acc[4];
#pragma unroll
    for (int nt = 0; nt < 4; nt++)
#pragma unroll
      for (int i = 0; i < 16; i++) acc[nt][i] = 0.0f;
    const _Float16* wl = wf + l * (9 * BSTG);

    for (int r = 0; r < 9; r++) {
      // ---- issue next-set staging loads (r+1, or l=1's r=0 at the layer boundary) ----
      f16x8 sta, stb;
      bool haveNext = (r < 8) || (l == 0);
      if (haveNext) {
        const _Float16* wn = (r < 8) ? (wl + (r + 1) * BSTG) : (wf + 9 * BSTG);
        sta = *((const f16x8*)(wn + tid * 8));
        stb = *((const f16x8*)(wn + 8192 + tid * 8));
      }
      // ---- gather this lane's K-half A row for relation r ----
      f16x8 a[4];
      if (r < 8) {
        gather4(a, Ap, csrS, offsS, r * P_ + myD, rowAct, cbck);
      } else {
        const _Float16* hp = &Ap[rowA * HROW + cbck];
#pragma unroll
        for (int kt = 0; kt < 4; kt++) a[kt] = *((const f16x8*)(hp + kt * 16));
      }
      // ---- 16 MFMAs (this wave's kt range) from the resident parity buffer ----
      const _Float16* bp = (r & 1) ? balt : Bstage;
      __builtin_amdgcn_s_setprio(1);
#pragma unroll
      for (int kt = 0; kt < 4; kt++) {
#pragma unroll
        for (int nt = 0; nt < 4; nt++) {
          f16x8 b = *((const f16x8*)&bp[(((ktBase + kt) * 4 + nt) * 64 + lane) * 8]);
          acc[nt] = __builtin_amdgcn_mfma_f32_32x32x16_f16(a[kt], b, acc[nt], 0, 0, 0);
        }
      }
      __builtin_amdgcn_s_setprio(0);
      // ---- commit staged B to P(r+1); one barrier per relation ----
      if (r < 8) {
        _Float16* dst = (r & 1) ? Bstage : balt;
        *((f16x8*)(dst + tid * 8)) = sta;
        *((f16x8*)(dst + 8192 + tid * 8)) = stb;
        __syncthreads();
      } else {
        __syncthreads();   // all waves done reading Bstage(r=8) and all gathers of Ap
        if (l == 0) {
          *((f16x8*)(Bstage + tid * 8)) = sta;      // (l=1, r=0)
          *((f16x8*)(Bstage + 8192 + tid * 8)) = stb;  // visible after combine barriers
        }
      }
    }

    if (l == 0) {
      // ---- K-half combine: c32 staging in dead hbuf0; 2 rounds of 4 tiles ----
      float* c32 = (float*)hbuf0;   // 4 slots x 25 rows x 128 cols f32 = 51200 B
      int slot = t8 & 3;
      // round 0: tiles 0-3
      if (wave < 4) {
#pragma unroll
        for (int nt = 0; nt < 4; nt++) {
          int col = nt * 32 + m32;
#pragma unroll
          for (int reg = 0; reg < 16; reg++) {
            int row = (reg & 3) + 8 * (reg >> 2) + 4 * kh;
            if (row < 25) c32[slot * 3200 + row * 128 + col] = acc[nt][reg];
          }
        }
      }
      __syncthreads();
      if (wave >= 8 && wave < 12) {
#pragma unroll
        for (int nt = 0; nt < 4; nt++) {
          int col = nt * 32 + m32;
          float bias = b1[col];
#pragma unroll
          for (int reg = 0; reg < 16; reg++) {
            int row = (reg & 3) + 8 * (reg >> 2) + 4 * kh;
            if (row < 25) {
              float v = c32[slot * 3200 + row * 128 + col] + acc[nt][reg] + bias;
              v = v > 0.0f ? v : 0.0f;
              hbuf1[(jobBase + row) * HROW + col] = (_Float16)v;
            }
          }
        }
      }
      __syncthreads();
      // round 1: tiles 4-7
      if (wave >= 4 && wave < 8) {
#pragma unroll
        for (int nt = 0; nt < 4; nt++) {
          int col = nt * 32 + m32;
#pragma unroll
          for (int reg = 0; reg < 16; reg++) {
            int row = (reg & 3) + 8 * (reg >> 2) + 4 * kh;
            if (row < 25) c32[slot * 3200 + row * 128 + col] = acc[nt][reg];
          }
        }
      }
      __syncthreads();
      if (wave >= 12) {
#pragma unroll
        for (int nt = 0; nt < 4; nt++) {
          int col = nt * 32 + m32;
          float bias = b1[col];
#pragma unroll
          for (int reg = 0; reg < 16; reg++) {
            int row = (reg & 3) + 8 * (reg >> 2) + 4 * kh;
            if (row < 25) {
              float v = c32[slot * 3200 + row * 128 + col] + acc[nt][reg] + bias;
              v = v > 0.0f ? v : 0.0f;
              hbuf1[(jobBase + row) * HROW + col] = (_Float16)v;
            }
          }
        }
      }
      __syncthreads();   // h' complete (and Bstage l1r0 visible) before layer-2
    } else {
      // ---- partial scores (linear in acc -> K-halves just add) ----
      float db2 = msgS[F_];
#pragma unroll
      for (int reg = 0; reg < 16; reg++) {
        int row = (reg & 3) + 8 * (reg >> 2) + 4 * kh;
        float p = 0.0f;
#pragma unroll
        for (int nt = 0; nt < 4; nt++)
          p += acc[nt][reg] * msgS[nt * 32 + m32];
        p += __shfl_xor(p, 16, 32);
        p += __shfl_xor(p, 8, 32);
        p += __shfl_xor(p, 4, 32);
        p += __shfl_xor(p, 2, 32);
        p += __shfl_xor(p, 1, 32);
        if (m32 == 0 && row < 25)
          scoreS[H * P_ + jobBase + row] = p;
      }
      __syncthreads();
      if (tid < P_)
        out[g * P_ + tid] = scoreS[tid] + scoreS[P_ + tid] + db2;
    }
  }
}

extern "C" void kernel_launch(void* const* d_in, const int* in_sizes, int n_in,
                              void* d_out, int out_size, void* d_ws, size_t ws_size,
                              hipStream_t stream) {
  const float* message = (const float*)d_in[0];
  const float* x       = (const float*)d_in[1];
  const int*   ei      = (const int*)d_in[2];
  const int*   et      = (const int*)d_in[3];
  const float* W1      = (const float*)d_in[6];
  const float* root1   = (const float*)d_in[7];
  const float* b1      = (const float*)d_in[8];
  const float* W2      = (const float*)d_in[9];
  const float* root2   = (const float*)d_in[10];
  const float* b2      = (const float*)d_in[11];
  const float* embed   = (const float*)d_in[12];
  const float* cw      = (const float*)d_in[13];
  const float* cb      = (const float*)d_in[14];
  const float* mw      = (const float*)d_in[15];
  const float* mb      = (const float*)d_in[16];

  _Float16* wfrag = (_Float16*)d_ws;   // 589,824 B
  float*    out   = (float*)d_out;

  hipLaunchKernelGGL(k_wstage, dim3(1152), dim3(256), 0, stream, W1, root1, W2, root2, wfrag);
  hipLaunchKernelGGL(k_main, dim3(G_), dim3(1024), 0, stream, x, ei, et, wfrag, b1, b2,
                     message, embed, cw, cb, mw, mb, out);
}

// Round 12
// 169.785 us; speedup vs baseline: 1.0697x; 1.0697x over previous
//
#include <hip/hip_runtime.h>
#include <stdint.h>

#define G_   250
#define P_   200
#define EPG  3200
#define E_   800000
#define F_   128
#define R_   8
#define HROW 136   // f16 elems per row; 272 B stride, 16B-aligned rows
#define NKEY (R_ * P_)   // 1600 (rel,dst) buckets
#define BSTG (8 * 4 * 64 * 8)   // 16384 f16 = 32 KB per (l,r) B-fragment set

typedef _Float16 f16x8 __attribute__((ext_vector_type(8)));
typedef _Float16 f16x4 __attribute__((ext_vector_type(4)));
typedef float    f32x4 __attribute__((ext_vector_type(4)));
typedef float    f32x16 __attribute__((ext_vector_type(16)));

// ---------------- prepass: W -> B-fragment layout for mfma_f32_32x32x16_f16 ----------------
// flat = ((((l*9+r)*8 + kt)*4 + ntj)*64 + lane)*8 + j
// value = W[r][k = kt*16 + (lane>>5)*8 + j][n = ntj*32 + (lane&31)]  (r==8 -> root)
// Vectorized x8: thread owns (l,r,kt,ntj,lane), loops j. Reads: lane-consecutive in n
// (coalesced 2x128B segments per j-step); write: one contiguous f16x8 (1 KB/wave-inst).
// Old version had j innermost -> 512B-strided reads (64 lines/wave-load) + 2B scattered writes.
__global__ __launch_bounds__(256) void k_wstage(const float* __restrict__ W1, const float* __restrict__ root1,
                                                const float* __restrict__ W2, const float* __restrict__ root2,
                                                _Float16* __restrict__ wf) {
  int tt = blockIdx.x * 256 + threadIdx.x;   // 144*256 = 36864 = 2*9*8*4*64
  int lane = tt & 63;
  int ntj  = (tt >> 6) & 3;
  int kt   = (tt >> 8) & 7;
  int rl   = tt >> 11;          // l*9 + r, 0..17
  int r = rl % 9, l = rl / 9;
  const float* Wl = (l == 0) ? W1 : W2;
  const float* rt = (l == 0) ? root1 : root2;
  int kbase = kt * 16 + (lane >> 5) * 8;
  int n = ntj * 32 + (lane & 31);
  f16x8 v;
#pragma unroll
  for (int j = 0; j < 8; j++) {
    float f = (r < 8) ? Wl[(r * F_ + kbase + j) * F_ + n] : rt[(kbase + j) * F_ + n];
    v[j] = (_Float16)f;
  }
  *((f16x8*)(wf + (((rl * 8 + kt) * 4 + ntj) * 64 + lane) * 8)) = v;
}

// ---- gather+mean one relation's A-fragments for one dst row into a named register set ----
__device__ __forceinline__ void gather_rel(f16x8 (&a)[8], const _Float16* __restrict__ Ap,
                                           const unsigned short* __restrict__ csr,
                                           const int* __restrict__ offs,
                                           int key, bool rowAct, int ck) {
  int o = 0, n = 0;
  if (rowAct) { o = offs[key]; n = offs[key + 1] - o; }
  f16x8 z = {0, 0, 0, 0, 0, 0, 0, 0};
#pragma unroll
  for (int kt = 0; kt < 8; kt++) a[kt] = z;
  int t = 0;
  for (; t + 2 <= n; t += 2) {
    int s0 = (int)csr[o + t];
    int s1 = (int)csr[o + t + 1];
    const _Float16* hp0 = &Ap[s0 * HROW + ck];
    const _Float16* hp1 = &Ap[s1 * HROW + ck];
    f16x8 u0[8], u1[8];
#pragma unroll
    for (int kt = 0; kt < 8; kt++) u0[kt] = *((const f16x8*)(hp0 + kt * 16));
#pragma unroll
    for (int kt = 0; kt < 8; kt++) u1[kt] = *((const f16x8*)(hp1 + kt * 16));
#pragma unroll
    for (int kt = 0; kt < 8; kt++) a[kt] += u0[kt] + u1[kt];
  }
  if (t < n) {
    int s0 = (int)csr[o + t];
    const _Float16* hp0 = &Ap[s0 * HROW + ck];
#pragma unroll
    for (int kt = 0; kt < 8; kt++) a[kt] += *((const f16x8*)(hp0 + kt * 16));
  }
  float nf = (n > 0) ? 1.0f / (float)n : 0.0f;
  _Float16 nh = (_Float16)nf;
#pragma unroll
  for (int kt = 0; kt < 8; kt++) a[kt] *= nh;
}

__device__ __forceinline__ void gather_root(f16x8 (&a)[8], const _Float16* __restrict__ Ap,
                                            int rowA, int ck) {
  const _Float16* hp = &Ap[rowA * HROW + ck];
#pragma unroll
  for (int kt = 0; kt < 8; kt++) a[kt] = *((const f16x8*)(hp + kt * 16));
}

// ---- one relation's 32 MFMAs; B frags chunk-read from the LDS parity buffer ----
__device__ __forceinline__ void mfma_rel(f32x16 (&acc)[4], const f16x8 (&a)[8],
                                         const _Float16* __restrict__ bp, int lane) {
  __builtin_amdgcn_s_setprio(1);
#pragma unroll
  for (int kt = 0; kt < 8; kt++) {
#pragma unroll
    for (int nt = 0; nt < 4; nt++) {
      f16x8 b = *((const f16x8*)&bp[((kt * 4 + nt) * 64 + lane) * 8]);
      acc[nt] = __builtin_amdgcn_mfma_f32_32x32x16_f16(a[kt], b, acc[nt], 0, 0, 0);
    }
  }
  __builtin_amdgcn_s_setprio(0);
}

// ---------------- main: one workgroup = one graph; 8 waves x 25 rows ----------------
// Software-pipelined r-loop: MFMA(r) consumes the a-set gathered LAST iteration while
// gather(r+1) fills the other named set -> MFMA has no dependency on this iteration's
// gather, so the scheduler can interleave gather ds_reads into the MFMA shadow.
// B double-buffered through LDS: even r -> Bstage, odd r -> dead-hbuf alias. 2 barriers/pair.
__global__ __launch_bounds__(512, 1) void k_main(
    const float* __restrict__ x, const int* __restrict__ ei, const int* __restrict__ et,
    const _Float16* __restrict__ wf, const float* __restrict__ b1, const float* __restrict__ b2,
    const float* __restrict__ message, const float* __restrict__ embed,
    const float* __restrict__ cw, const float* __restrict__ cb,
    const float* __restrict__ mw, const float* __restrict__ mb,
    float* __restrict__ out) {
  __shared__ __attribute__((aligned(16))) _Float16 hbuf0[P_ * HROW];  // 54400 B
  __shared__ __attribute__((aligned(16))) _Float16 hbuf1[P_ * HROW];  // 54400 B
  __shared__ __attribute__((aligned(16))) _Float16 Bstage[BSTG];      // 32768 B
  __shared__ unsigned short csrS[EPG];                                // 6400 B
  __shared__ int offsS[NKEY + 1];                                     // 6404 B
  __shared__ float msgS[F_ + 1];                                      // 516 B  -> 154888 B

  int g = blockIdx.x, tid = threadIdx.x;
  int lane = tid & 63, wave = tid >> 6;
  int m32 = lane & 31, kh = lane >> 5;

  // ---- setup scratch aliased inside hbuf1 (dead until first odd-B commit) ----
  int*   Sint = (int*)hbuf1;
  int*   cnt  = Sint;                    // [1600]
  int*   cur  = Sint + 1600;             // [1600]
  int*   eRec = Sint + 3200;             // [3200]
  float* comb = (float*)(Sint + 6400);   // [256]
  float* red  = (float*)(Sint + 6656);   // [128]   => 27136 B < 54400 B

  // ---- issue (l=0, r=0) B-fragment loads immediately (land during phase 0) ----
  f16x8 st0[4];
#pragma unroll
  for (int i = 0; i < 4; i++)
    st0[i] = *((const f16x8*)(wf + i * 4096 + tid * 8));

  // ---- phase 0: stage x -> hbuf0 (f16); zero cnt/cur; msg combined features ----
  for (int i = tid; i < P_ * 32; i += 512) {
    int row = i >> 5, c4 = i & 31;
    const float4 v = ((const float4*)x)[(g * P_ + row) * 32 + c4];
    f16x4 pk = { (_Float16)v.x, (_Float16)v.y, (_Float16)v.z, (_Float16)v.w };
    *((f16x4*)&hbuf0[row * HROW + c4 * 4]) = pk;
  }
  for (int i = tid; i < NKEY; i += 512) { cnt[i] = 0; cur[i] = 0; }
  if (tid < F_) {
    int tok = (int)message[g * 2];
    float cont = message[g * 2 + 1];
    comb[tid] = embed[tok * F_ + tid];
    float ce = cont * cw[tid] + cb[tid];
    comb[F_ + tid] = ce > 0.0f ? ce : 0.0f;
  }
#pragma unroll
  for (int i = 0; i < 4; i++)
    *((f16x8*)(Bstage + i * 4096 + tid * 8)) = st0[i];
  __syncthreads();

  // ---- phase 1 (wave-specialized): edge ingest || message matmul ----
  int base = g * EPG, nbase = g * P_;
  if (wave < 6) {
    for (int e = wave * 64 + lane; e < EPG; e += 384) {
      int s = ei[base + e] - nbase;
      int d = ei[E_ + base + e] - nbase;
      int r = et[base + e];
      eRec[e] = s | (d << 8) | (r << 16);
      atomicAdd(&cnt[r * P_ + d], 1);
    }
  } else {
    int col = tid & 127;
    float acc = 0.0f;
#pragma unroll 16
    for (int k2 = 0; k2 < 256; k2++) acc += comb[k2] * mw[k2 * F_ + col];
    red[col] = acc;
  }
  __syncthreads();

  // ---- phase 2: wave0 = offset scan (shfl); wave1 = msg finalize ----
  if (wave == 0) {
    int4 vv[8];
    int osum = 0;
    if (lane < 50) {
      const int4* cp = (const int4*)(cnt + lane * 32);
#pragma unroll
      for (int i = 0; i < 8; i++) { vv[i] = cp[i]; osum += vv[i].x + vv[i].y + vv[i].z + vv[i].w; }
    }
    int incl = osum;
#pragma unroll
    for (int d = 1; d < 64; d <<= 1) {
      int t2 = __shfl_up(incl, d, 64);
      if (lane >= d) incl += t2;
    }
    int run = incl - osum;   // exclusive prefix
    if (lane < 50) {
#pragma unroll
      for (int i = 0; i < 8; i++) {
        offsS[lane * 32 + i * 4 + 0] = run; run += vv[i].x;
        offsS[lane * 32 + i * 4 + 1] = run; run += vv[i].y;
        offsS[lane * 32 + i * 4 + 2] = run; run += vv[i].z;
        offsS[lane * 32 + i * 4 + 3] = run; run += vv[i].w;
      }
    }
    if (lane == 0) offsS[NKEY] = EPG;
  } else if (wave == 1) {
    float m0 = mb[lane] + red[lane];
    float m1 = mb[lane + 64] + red[lane + 64];
    m0 = m0 > 0.0f ? m0 : 0.0f;
    m1 = m1 > 0.0f ? m1 : 0.0f;
    msgS[lane] = m0; msgS[lane + 64] = m1;
    float p = m0 * b2[lane] + m1 * b2[lane + 64];
#pragma unroll
    for (int d = 32; d > 0; d >>= 1) p += __shfl_xor(p, d, 64);
    if (lane == 0) msgS[F_] = p;
  }
  __syncthreads();

  // ---- phase 3: CSR scatter from LDS records ----
  for (int e = tid; e < EPG; e += 512) {
    int rec = eRec[e];
    int s = rec & 255, d = (rec >> 8) & 255, r = rec >> 16;
    int key = r * P_ + d;
    int pos = atomicAdd(&cur[key], 1);
    csrS[offsS[key] + pos] = (unsigned short)s;
  }
  __syncthreads();   // hbuf0 + csr + offs + msg + Bstage(l0,r0) ready; hbuf1 scratch dead

  // ---- fused layers: wave w owns rows [w*25, w*25+25); pipelined r-loop ----
  int jobBase = wave * 25;
  bool rowAct = (m32 < 25);
  int myD = jobBase + m32;
  int ck = kh * 8;
  int rowA = jobBase + (rowAct ? m32 : 24);

  for (int l = 0; l < 2; l++) {
    const _Float16* Ap = (l == 0) ? hbuf0 : hbuf1;
    _Float16* balt = (l == 0) ? hbuf1 : hbuf0;   // odd-r B buffer aliases the dead hbuf
    f32x16 acc[4];
#pragma unroll
    for (int nt = 0; nt < 4; nt++)
#pragma unroll
      for (int i = 0; i < 16; i++) acc[nt][i] = 0.0f;
    const _Float16* wl = wf + l * (9 * BSTG);

    f16x8 aA[8], aB[8];
    gather_rel(aA, Ap, csrS, offsS, 0 * P_ + myD, rowAct, ck);   // prologue: r=0

    for (int p = 0; p < 4; p++) {
      int r1 = 2 * p + 1;
      // -- even half: MFMA(2p) from Bstage; stage B(2p+1)->balt; gather(2p+1)->aB --
      f16x8 st2[4];
      {
        const _Float16* wn = wl + r1 * BSTG;
#pragma unroll
        for (int i = 0; i < 4; i++)
          st2[i] = *((const f16x8*)(wn + i * 4096 + tid * 8));
      }
      mfma_rel(acc, aA, Bstage, lane);
      gather_rel(aB, Ap, csrS, offsS, r1 * P_ + myD, rowAct, ck);
#pragma unroll
      for (int i = 0; i < 4; i++)
        *((f16x8*)(balt + i * 4096 + tid * 8)) = st2[i];
      __syncthreads();
      // -- odd half: MFMA(2p+1) from balt; stage B(2p+2)->Bstage; gather(2p+2)->aA --
      {
        const _Float16* wn = wl + (r1 + 1) * BSTG;
#pragma unroll
        for (int i = 0; i < 4; i++)
          st2[i] = *((const f16x8*)(wn + i * 4096 + tid * 8));
      }
      mfma_rel(acc, aB, balt, lane);
      if (p < 3)
        gather_rel(aA, Ap, csrS, offsS, (2 * p + 2) * P_ + myD, rowAct, ck);
      else
        gather_root(aA, Ap, rowA, ck);   // pipeline slot for r=8 (root)
#pragma unroll
      for (int i = 0; i < 4; i++)
        *((f16x8*)(Bstage + i * 4096 + tid * 8)) = st2[i];
      __syncthreads();
    }
    // -- final r=8 (root): B(8) resident in Bstage --
    if (l == 0) {
      f16x8 st3[4];
      const _Float16* wn = wf + 9 * BSTG;   // (l=1, r=0)
#pragma unroll
      for (int i = 0; i < 4; i++)
        st3[i] = *((const f16x8*)(wn + i * 4096 + tid * 8));
      mfma_rel(acc, aA, Bstage, lane);
      __syncthreads();   // all waves done reading Bstage(8) and all l=0 gathers of hbuf0/hbuf1-B
#pragma unroll
      for (int i = 0; i < 4; i++)
        *((f16x8*)(Bstage + i * 4096 + tid * 8)) = st3[i];   // visible after epilogue barrier
      // epilogue: h' = relu(acc + b1) -> hbuf1
#pragma unroll
      for (int nt = 0; nt < 4; nt++) {
        int col = nt * 32 + m32;
        float bias = b1[col];
#pragma unroll
        for (int reg = 0; reg < 16; reg++) {
          int row = (reg & 3) + 8 * (reg >> 2) + 4 * kh;
          if (row < 25) {
            float v = acc[nt][reg] + bias;
            v = v > 0.0f ? v : 0.0f;
            hbuf1[(jobBase + row) * HROW + col] = (_Float16)v;
          }
        }
      }
      __syncthreads();   // h' + Bstage(l1,r0) complete before layer-2 gathers/MFMA
    } else {
      mfma_rel(acc, aA, Bstage, lane);
      // score = dot(node_emb, msg) + dot(b2, msg)
      float db2 = msgS[F_];
#pragma unroll
      for (int reg = 0; reg < 16; reg++) {
        int row = (reg & 3) + 8 * (reg >> 2) + 4 * kh;
        float p = 0.0f;
#pragma unroll
        for (int nt = 0; nt < 4; nt++)
          p += acc[nt][reg] * msgS[nt * 32 + m32];
        p += __shfl_xor(p, 16, 32);
        p += __shfl_xor(p, 8, 32);
        p += __shfl_xor(p, 4, 32);
        p += __shfl_xor(p, 2, 32);
        p += __shfl_xor(p, 1, 32);
        if (m32 == 0 && row < 25)
          out[g * P_ + jobBase + row] = p + db2;
      }
    }
  }
}

extern "C" void kernel_launch(void* const* d_in, const int* in_sizes, int n_in,
                              void* d_out, int out_size, void* d_ws, size_t ws_size,
                              hipStream_t stream) {
  const float* message = (const float*)d_in[0];
  const float* x       = (const float*)d_in[1];
  const int*   ei      = (const int*)d_in[2];
  const int*   et      = (const int*)d_in[3];
  const float* W1      = (const float*)d_in[6];
  const float* root1   = (const float*)d_in[7];
  const float* b1      = (const float*)d_in[8];
  const float* W2      = (const float*)d_in[9];
  const float* root2   = (const float*)d_in[10];
  const float* b2      = (const float*)d_in[11];
  const float* embed   = (const float*)d_in[12];
  const float* cw      = (const float*)d_in[13];
  const float* cb      = (const float*)d_in[14];
  const float* mw      = (const float*)d_in[15];
  const float* mb      = (const float*)d_in[16];

  _Float16* wfrag = (_Float16*)d_ws;   // 589,824 B
  float*    out   = (float*)d_out;

  hipLaunchKernelGGL(k_wstage, dim3(144), dim3(256), 0, stream, W1, root1, W2, root2, wfrag);
  hipLaunchKernelGGL(k_main, dim3(G_), dim3(512), 0, stream, x, ei, et, wfrag, b1, b2,
                     message, embed, cw, cb, mw, mb, out);
}